// Round 2
// baseline (9399.158 us; speedup 1.0000x reference)
//
#include <hip/hip_runtime.h>

#define NN 50000
#define NE 800000
#define DIN 32
#define DD 96
#define NL 4
#define NCLS 10
#define EPSF 1e-6f

typedef unsigned short u16;
typedef unsigned int u32;

static __device__ __forceinline__ float bf2f(u16 u) {
    return __uint_as_float(((u32)u) << 16);
}
static __device__ __forceinline__ u16 f2bf(float f) {
    u32 x = __float_as_uint(f);
    x += 0x7FFFu + ((x >> 16) & 1u);   // round-to-nearest-even
    return (u16)(x >> 16);
}

__global__ void k_zero(float4* __restrict__ p, int n4) {
    int i = blockIdx.x * blockDim.x + threadIdx.x;
    if (i < n4) p[i] = make_float4(0.f, 0.f, 0.f, 0.f);
}

// input projection: Y[row,j] = X[row,:K=32] @ W[32,96] + B ; out f32 or bf16
template <bool BFOUT>
__global__ void k_proj(const float* __restrict__ X, const float* __restrict__ W,
                       const float* __restrict__ B, void* __restrict__ Y, long total) {
    long idx = (long)blockIdx.x * blockDim.x + threadIdx.x;
    if (idx >= total) return;
    int row = (int)(idx / DD);
    int j = (int)(idx - (long)row * DD);
    const float* xr = X + (long)row * DIN;
    float acc = B[j];
#pragma unroll
    for (int k = 0; k < DIN; ++k) acc = fmaf(xr[k], W[k * DD + j], acc);
    if (BFOUT) ((u16*)Y)[idx] = f2bf(acc);
    else       ((float*)Y)[idx] = acc;
}

// tiled GEMM: Y[nrows,96] = X[nrows,96] @ W[96,96] + B
// block 192 thr, 32-row tile, 4x4 micro-tile per thread. W + X tile in LDS.
template <bool BFOUT>
__global__ __launch_bounds__(192) void k_gemm96(const float* __restrict__ X,
                                                const float* __restrict__ W,
                                                const float* __restrict__ B,
                                                void* __restrict__ Y, int nrows) {
    __shared__ float ws_w[DD * DD];      // 36 KB
    __shared__ float xs[32 * 100];       // 12.8 KB (pad 100 vs bank conflicts)
    const int tid = threadIdx.x;
    const int row0 = blockIdx.x * 32;
    {
        const float4* Wv = (const float4*)W;
        float4* wv = (float4*)ws_w;
#pragma unroll
        for (int t = 0; t < 12; ++t) wv[tid + t * 192] = Wv[tid + t * 192];
    }
#pragma unroll
    for (int t = 0; t < 4; ++t) {
        int q = tid + t * 192;
        int r = q / 24, c4 = q - r * 24;
        int row = row0 + r;
        float4 v = make_float4(0.f, 0.f, 0.f, 0.f);
        if (row < nrows) v = *(const float4*)&X[(long)row * DD + c4 * 4];
        *(float4*)&xs[r * 100 + c4 * 4] = v;
    }
    __syncthreads();
    const int je = tid % 24, ge = tid / 24;
    const int j0 = je * 4, r0 = ge * 4;
    float acc[4][4] = {};
#pragma unroll 4
    for (int k4 = 0; k4 < 24; ++k4) {
        const int kk = k4 * 4;
        float4 a0 = *(const float4*)&xs[(r0 + 0) * 100 + kk];
        float4 a1 = *(const float4*)&xs[(r0 + 1) * 100 + kk];
        float4 a2 = *(const float4*)&xs[(r0 + 2) * 100 + kk];
        float4 a3 = *(const float4*)&xs[(r0 + 3) * 100 + kk];
        float4 w0 = *(const float4*)&ws_w[(kk + 0) * DD + j0];
        float4 w1 = *(const float4*)&ws_w[(kk + 1) * DD + j0];
        float4 w2 = *(const float4*)&ws_w[(kk + 2) * DD + j0];
        float4 w3 = *(const float4*)&ws_w[(kk + 3) * DD + j0];
#define ROWFMA(i, a)                                                                  \
    acc[i][0] = fmaf(a.x, w0.x, fmaf(a.y, w1.x, fmaf(a.z, w2.x, fmaf(a.w, w3.x, acc[i][0])))); \
    acc[i][1] = fmaf(a.x, w0.y, fmaf(a.y, w1.y, fmaf(a.z, w2.y, fmaf(a.w, w3.y, acc[i][1])))); \
    acc[i][2] = fmaf(a.x, w0.z, fmaf(a.y, w1.z, fmaf(a.z, w2.z, fmaf(a.w, w3.z, acc[i][2])))); \
    acc[i][3] = fmaf(a.x, w0.w, fmaf(a.y, w1.w, fmaf(a.z, w2.w, fmaf(a.w, w3.w, acc[i][3]))));
        ROWFMA(0, a0) ROWFMA(1, a1) ROWFMA(2, a2) ROWFMA(3, a3)
#undef ROWFMA
    }
    const float b0 = B[j0], b1 = B[j0 + 1], b2 = B[j0 + 2], b3 = B[j0 + 3];
#pragma unroll
    for (int i = 0; i < 4; ++i) {
        int row = row0 + r0 + i;
        if (row >= nrows) continue;
        float v0 = acc[i][0] + b0, v1 = acc[i][1] + b1;
        float v2 = acc[i][2] + b2, v3 = acc[i][3] + b3;
        if (BFOUT) {
            u32 p0 = (u32)f2bf(v0) | ((u32)f2bf(v1) << 16);
            u32 p1 = (u32)f2bf(v2) | ((u32)f2bf(v3) << 16);
            *(uint2*)((u16*)Y + (long)row * DD + j0) = make_uint2(p0, p1);
        } else {
            *(float4*)((float*)Y + (long)row * DD + j0) = make_float4(v0, v1, v2, v3);
        }
    }
}

// fused edge kernel: e_new = e@Cw + Cb + Dh[src] + Eh[dst]; sigma = sigmoid;
// atomics into num/den[dst]; e += relu(e_new) in place (bf16 state).
__global__ __launch_bounds__(192) void k_edge(u16* ebuf,  // in/out, no restrict
                                              const float* __restrict__ Cw,
                                              const float* __restrict__ Cb,
                                              const u16* __restrict__ Dh,
                                              const u16* __restrict__ Eh,
                                              const u16* __restrict__ Bh,
                                              const int* __restrict__ src,
                                              const int* __restrict__ dst,
                                              float* __restrict__ num,
                                              float* __restrict__ den) {
    __shared__ float cw[DD * DD];
    __shared__ float xs[32 * 100];
    __shared__ int ssrc[32], sdst[32];
    const int tid = threadIdx.x;
    const int e0 = blockIdx.x * 32;
    {
        const float4* Wv = (const float4*)Cw;
        float4* wv = (float4*)cw;
#pragma unroll
        for (int t = 0; t < 12; ++t) wv[tid + t * 192] = Wv[tid + t * 192];
    }
#pragma unroll
    for (int t = 0; t < 2; ++t) {
        int q = tid + t * 192;
        int r = q / 12, c8 = q - r * 12;
        const uint4 u = *(const uint4*)&ebuf[(long)(e0 + r) * DD + c8 * 8];
        float* xp = &xs[r * 100 + c8 * 8];
        xp[0] = bf2f((u16)(u.x & 0xFFFF)); xp[1] = bf2f((u16)(u.x >> 16));
        xp[2] = bf2f((u16)(u.y & 0xFFFF)); xp[3] = bf2f((u16)(u.y >> 16));
        xp[4] = bf2f((u16)(u.z & 0xFFFF)); xp[5] = bf2f((u16)(u.z >> 16));
        xp[6] = bf2f((u16)(u.w & 0xFFFF)); xp[7] = bf2f((u16)(u.w >> 16));
    }
    if (tid < 32) ssrc[tid] = src[e0 + tid];
    else if (tid < 64) sdst[tid - 32] = dst[e0 + tid - 32];
    __syncthreads();
    const int je = tid % 24, ge = tid / 24;
    const int j0 = je * 4, r0 = ge * 4;
    float acc[4][4] = {};
#pragma unroll 4
    for (int k4 = 0; k4 < 24; ++k4) {
        const int kk = k4 * 4;
        float4 a0 = *(const float4*)&xs[(r0 + 0) * 100 + kk];
        float4 a1 = *(const float4*)&xs[(r0 + 1) * 100 + kk];
        float4 a2 = *(const float4*)&xs[(r0 + 2) * 100 + kk];
        float4 a3 = *(const float4*)&xs[(r0 + 3) * 100 + kk];
        float4 w0 = *(const float4*)&cw[(kk + 0) * DD + j0];
        float4 w1 = *(const float4*)&cw[(kk + 1) * DD + j0];
        float4 w2 = *(const float4*)&cw[(kk + 2) * DD + j0];
        float4 w3 = *(const float4*)&cw[(kk + 3) * DD + j0];
#define ROWFMA(i, a)                                                                  \
    acc[i][0] = fmaf(a.x, w0.x, fmaf(a.y, w1.x, fmaf(a.z, w2.x, fmaf(a.w, w3.x, acc[i][0])))); \
    acc[i][1] = fmaf(a.x, w0.y, fmaf(a.y, w1.y, fmaf(a.z, w2.y, fmaf(a.w, w3.y, acc[i][1])))); \
    acc[i][2] = fmaf(a.x, w0.z, fmaf(a.y, w1.z, fmaf(a.z, w2.z, fmaf(a.w, w3.z, acc[i][2])))); \
    acc[i][3] = fmaf(a.x, w0.w, fmaf(a.y, w1.w, fmaf(a.z, w2.w, fmaf(a.w, w3.w, acc[i][3]))));
        ROWFMA(0, a0) ROWFMA(1, a1) ROWFMA(2, a2) ROWFMA(3, a3)
#undef ROWFMA
    }
    const float cb0 = Cb[j0], cb1 = Cb[j0 + 1], cb2 = Cb[j0 + 2], cb3 = Cb[j0 + 3];
#pragma unroll
    for (int i = 0; i < 4; ++i) {
        const int el = r0 + i;
        const long eg = e0 + el;
        const int s = ssrc[el], t = sdst[el];
        const uint2 du = *(const uint2*)&Dh[(long)s * DD + j0];
        const uint2 eu = *(const uint2*)&Eh[(long)t * DD + j0];
        const uint2 bu = *(const uint2*)&Bh[(long)s * DD + j0];
        float dh0 = bf2f((u16)(du.x & 0xFFFF)), dh1 = bf2f((u16)(du.x >> 16));
        float dh2 = bf2f((u16)(du.y & 0xFFFF)), dh3 = bf2f((u16)(du.y >> 16));
        float ev0 = bf2f((u16)(eu.x & 0xFFFF)), ev1 = bf2f((u16)(eu.x >> 16));
        float ev2 = bf2f((u16)(eu.y & 0xFFFF)), ev3 = bf2f((u16)(eu.y >> 16));
        float bh0 = bf2f((u16)(bu.x & 0xFFFF)), bh1 = bf2f((u16)(bu.x >> 16));
        float bh2 = bf2f((u16)(bu.y & 0xFFFF)), bh3 = bf2f((u16)(bu.y >> 16));
        float en0 = acc[i][0] + cb0 + dh0 + ev0;
        float en1 = acc[i][1] + cb1 + dh1 + ev1;
        float en2 = acc[i][2] + cb2 + dh2 + ev2;
        float en3 = acc[i][3] + cb3 + dh3 + ev3;
        float sg0 = 1.f / (1.f + __expf(-en0));
        float sg1 = 1.f / (1.f + __expf(-en1));
        float sg2 = 1.f / (1.f + __expf(-en2));
        float sg3 = 1.f / (1.f + __expf(-en3));
        float* np = num + (long)t * DD + j0;
        float* dp = den + (long)t * DD + j0;
        atomicAdd(np + 0, bh0 * sg0); atomicAdd(dp + 0, sg0);
        atomicAdd(np + 1, bh1 * sg1); atomicAdd(dp + 1, sg1);
        atomicAdd(np + 2, bh2 * sg2); atomicAdd(dp + 2, sg2);
        atomicAdd(np + 3, bh3 * sg3); atomicAdd(dp + 3, sg3);
        const float* xp = &xs[el * 100 + j0];
        float o0 = xp[0] + fmaxf(en0, 0.f), o1 = xp[1] + fmaxf(en1, 0.f);
        float o2 = xp[2] + fmaxf(en2, 0.f), o3 = xp[3] + fmaxf(en3, 0.f);
        u32 p0 = (u32)f2bf(o0) | ((u32)f2bf(o1) << 16);
        u32 p1 = (u32)f2bf(o2) | ((u32)f2bf(o3) << 16);
        *(uint2*)&ebuf[eg * DD + j0] = make_uint2(p0, p1);
    }
}

// h += relu(Ah + num/(den+eps)), vectorized
__global__ void k_combine(const float4* __restrict__ Ah, const float4* __restrict__ num,
                          const float4* __restrict__ den, float4* __restrict__ h, int n4) {
    int i = blockIdx.x * blockDim.x + threadIdx.x;
    if (i >= n4) return;
    float4 a = Ah[i], nm = num[i], dn = den[i], hv = h[i];
    hv.x += fmaxf(a.x + nm.x / (dn.x + EPSF), 0.f);
    hv.y += fmaxf(a.y + nm.y / (dn.y + EPSF), 0.f);
    hv.z += fmaxf(a.z + nm.z / (dn.z + EPSF), 0.f);
    hv.w += fmaxf(a.w + nm.w / (dn.w + EPSF), 0.f);
    h[i] = hv;
}

// small MLP stage, one thread per output element
__global__ void k_mlp(const float* __restrict__ X, const float* __restrict__ W,
                      const float* __restrict__ B, float* __restrict__ Y,
                      int K, int Dout, int act, long total) {
    long idx = (long)blockIdx.x * blockDim.x + threadIdx.x;
    if (idx >= total) return;
    int row = (int)(idx / Dout);
    int j = (int)(idx - (long)row * Dout);
    const float* xr = X + (long)row * K;
    float acc = B[j];
    for (int k = 0; k < K; ++k) acc = fmaf(xr[k], W[k * Dout + j], acc);
    if (act == 1) acc = fmaxf(acc, 0.f);
    else if (act == 2) acc = 1.f / (1.f + __expf(-acc));
    Y[idx] = acc;
}

extern "C" void kernel_launch(void* const* d_in, const int* in_sizes, int n_in,
                              void* d_out, int out_size, void* d_ws, size_t ws_size,
                              hipStream_t stream) {
    const float* h_in = (const float*)d_in[0];
    const float* e_in = (const float*)d_in[1];
    const int* src = (const int*)d_in[2];
    const int* dst = (const int*)d_in[3];
    const float* fp_w = (const float*)d_in[4];
    const float* fp_b = (const float*)d_in[5];
    const float* ep_w = (const float*)d_in[6];
    const float* ep_b = (const float*)d_in[7];
    const float* A_w = (const float*)d_in[8];
    const float* A_b = (const float*)d_in[9];
    const float* B_w = (const float*)d_in[10];
    const float* B_b = (const float*)d_in[11];
    const float* C_w = (const float*)d_in[12];
    const float* C_b = (const float*)d_in[13];
    const float* D_w = (const float*)d_in[14];
    const float* D_b = (const float*)d_in[15];
    const float* E_w = (const float*)d_in[16];
    const float* E_b = (const float*)d_in[17];
    const float* mlp0_w = (const float*)d_in[18];
    const float* mlp0_b = (const float*)d_in[19];
    const float* mlp1_w = (const float*)d_in[20];
    const float* mlp1_b = (const float*)d_in[21];
    const float* mlp2_w = (const float*)d_in[22];
    const float* mlp2_b = (const float*)d_in[23];
    float* out = (float*)d_out;

    // workspace layout
    const size_t ND = (size_t)NN * DD;      // 4.8M
    const size_t ED = (size_t)NE * DD;      // 76.8M
    char* w = (char*)d_ws;
    float* hbuf = (float*)w; w += ND * 4;
    float* Ahb  = (float*)w; w += ND * 4;
    float* numb = (float*)w; w += ND * 4;   // numb & denb adjacent (single zero pass)
    float* denb = (float*)w; w += ND * 4;
    u16* Bhb = (u16*)w; w += ND * 2;
    u16* Dhb = (u16*)w; w += ND * 2;
    u16* Ehb = (u16*)w; w += ND * 2;
    u16* ebuf = (u16*)w; w += ED * 2;
    size_t need = (size_t)(w - (char*)d_ws);
    if (ws_size < need) return;  // uniform across calls -> graph-safe; fails absmax as diagnostic

    const long totH = (long)ND, totE = (long)ED;
    k_proj<false><<<(int)((totH + 255) / 256), 256, 0, stream>>>(h_in, fp_w, fp_b, hbuf, totH);
    k_proj<true><<<(int)((totE + 255) / 256), 256, 0, stream>>>(e_in, ep_w, ep_b, ebuf, totE);

    const int gN = (NN + 31) / 32;   // 1563
    const int gE = NE / 32;          // 25000
    const int zn4 = (int)(2 * ND / 4);

    for (int l = 0; l < NL; ++l) {
        const float* Aw = A_w + (size_t)l * DD * DD; const float* Ab = A_b + (size_t)l * DD;
        const float* Bw = B_w + (size_t)l * DD * DD; const float* Bb = B_b + (size_t)l * DD;
        const float* Cw = C_w + (size_t)l * DD * DD; const float* Cb = C_b + (size_t)l * DD;
        const float* Dw = D_w + (size_t)l * DD * DD; const float* Db = D_b + (size_t)l * DD;
        const float* Ew = E_w + (size_t)l * DD * DD; const float* Eb = E_b + (size_t)l * DD;

        k_gemm96<false><<<gN, 192, 0, stream>>>(hbuf, Aw, Ab, Ahb, NN);
        k_gemm96<true><<<gN, 192, 0, stream>>>(hbuf, Bw, Bb, Bhb, NN);
        k_gemm96<true><<<gN, 192, 0, stream>>>(hbuf, Dw, Db, Dhb, NN);
        k_gemm96<true><<<gN, 192, 0, stream>>>(hbuf, Ew, Eb, Ehb, NN);
        k_zero<<<(zn4 + 255) / 256, 256, 0, stream>>>((float4*)numb, zn4);
        k_edge<<<gE, 192, 0, stream>>>(ebuf, Cw, Cb, Dhb, Ehb, Bhb, src, dst, numb, denb);
        k_combine<<<(int)((ND / 4 + 255) / 256), 256, 0, stream>>>(
            (const float4*)Ahb, (const float4*)numb, (const float4*)denb, (float4*)hbuf,
            (int)(ND / 4));
    }

    // MLP readout (reuse numb/denb as temps)
    float* y1 = numb;  // [N,48]
    float* y2 = denb;  // [N,24]
    long t0 = (long)NN * 48, t1 = (long)NN * 24, t2 = (long)NN * NCLS;
    k_mlp<<<(int)((t0 + 255) / 256), 256, 0, stream>>>(hbuf, mlp0_w, mlp0_b, y1, DD, 48, 1, t0);
    k_mlp<<<(int)((t1 + 255) / 256), 256, 0, stream>>>(y1, mlp1_w, mlp1_b, y2, 48, 24, 1, t1);
    k_mlp<<<(int)((t2 + 255) / 256), 256, 0, stream>>>(y2, mlp2_w, mlp2_b, out, 24, NCLS, 2, t2);
}

// Round 3
// 3707.267 us; speedup vs baseline: 2.5353x; 2.5353x over previous
//
#include <hip/hip_runtime.h>

#define NN 50000
#define NE 800000
#define DIN 32
#define DD 96
#define NL 4
#define NCLS 10
#define EPSF 1e-6f

typedef unsigned short u16;
typedef unsigned int u32;

static __device__ __forceinline__ float bf2f(u16 u) {
    return __uint_as_float(((u32)u) << 16);
}
static __device__ __forceinline__ u16 f2bf(float f) {
    u32 x = __float_as_uint(f);
    x += 0x7FFFu + ((x >> 16) & 1u);   // round-to-nearest-even
    return (u16)(x >> 16);
}

__global__ void k_zero_i(int* __restrict__ p, int n) {
    int i = blockIdx.x * blockDim.x + threadIdx.x;
    if (i < n) p[i] = 0;
}

__global__ void k_hist(const int* __restrict__ dst, int* __restrict__ counts) {
    int i = blockIdx.x * blockDim.x + threadIdx.x;
    if (i < NE) atomicAdd(&counts[dst[i]], 1);
}

// single-block exclusive scan over n counts -> row_ptr[0..n], cursor copy.
__global__ __launch_bounds__(1024) void k_scan(const int* __restrict__ counts,
                                               int* __restrict__ row_ptr,
                                               int* __restrict__ cursor, int n) {
    __shared__ int wsum[16];
    __shared__ int carry_s;
    const int tid = threadIdx.x;
    const int lane = tid & 63, wid = tid >> 6;
    if (tid == 0) carry_s = 0;
    __syncthreads();
    for (int base = 0; base < n; base += 1024) {
        int i = base + tid;
        int v = (i < n) ? counts[i] : 0;
        int x = v;
#pragma unroll
        for (int off = 1; off < 64; off <<= 1) {
            int t = __shfl_up(x, (unsigned)off, 64);
            if (lane >= off) x += t;
        }
        if (lane == 63) wsum[wid] = x;
        __syncthreads();
        if (wid == 0 && lane < 16) {
            int s = wsum[lane];
#pragma unroll
            for (int off = 1; off < 16; off <<= 1) {
                int t = __shfl_up(s, (unsigned)off, 16);
                if (lane >= off) s += t;
            }
            wsum[lane] = s;
        }
        __syncthreads();
        int wbase = (wid > 0) ? wsum[wid - 1] : 0;
        int carry = carry_s;
        int excl = carry + wbase + x - v;
        if (i < n) { row_ptr[i] = excl; cursor[i] = excl; }
        __syncthreads();
        if (tid == 0) carry_s = carry + wsum[15];
        __syncthreads();
    }
    if (tid == 0) row_ptr[n] = carry_s;
}

__global__ void k_scatter(const int* __restrict__ src, const int* __restrict__ dst,
                          int* __restrict__ cursor, int* __restrict__ eperm,
                          int* __restrict__ srcp) {
    int i = blockIdx.x * blockDim.x + threadIdx.x;
    if (i >= NE) return;
    int pos = atomicAdd(&cursor[dst[i]], 1);
    eperm[pos] = i;
    srcp[pos] = src[i];
}

// node input projection: hbuf[row,j] = h_in[row,:32] @ fp_w + fp_b  (f32 out)
__global__ void k_proj_h(const float* __restrict__ X, const float* __restrict__ W,
                         const float* __restrict__ B, float* __restrict__ Y, long total) {
    long idx = (long)blockIdx.x * blockDim.x + threadIdx.x;
    if (idx >= total) return;
    int row = (int)(idx / DD);
    int j = (int)(idx - (long)row * DD);
    const float* xr = X + (long)row * DIN;
    float acc = B[j];
#pragma unroll
    for (int k = 0; k < DIN; ++k) acc = fmaf(xr[k], W[k * DD + j], acc);
    Y[idx] = acc;
}

// edge input projection into dst-sorted order: ebuf[i] = proj(e_in[eperm[i]]) (bf16)
__global__ void k_proj_e(const float* __restrict__ X, const float* __restrict__ W,
                         const float* __restrict__ B, u16* __restrict__ Y,
                         const int* __restrict__ eperm, long total) {
    long idx = (long)blockIdx.x * blockDim.x + threadIdx.x;
    if (idx >= total) return;
    int row = (int)(idx / DD);
    int j = (int)(idx - (long)row * DD);
    const float* xr = X + (long)eperm[row] * DIN;
    float acc = B[j];
#pragma unroll
    for (int k = 0; k < DIN; ++k) acc = fmaf(xr[k], W[k * DD + j], acc);
    Y[idx] = f2bf(acc);
}

// tiled GEMM: Y[nrows,96] = X[nrows,96] @ W[96,96] + B   (f32 or bf16 out)
template <bool BFOUT>
__global__ __launch_bounds__(192) void k_gemm96(const float* __restrict__ X,
                                                const float* __restrict__ W,
                                                const float* __restrict__ B,
                                                void* __restrict__ Y, int nrows) {
    __shared__ float ws_w[DD * DD];
    __shared__ float xs[32 * 100];
    const int tid = threadIdx.x;
    const int row0 = blockIdx.x * 32;
    {
        const float4* Wv = (const float4*)W;
        float4* wv = (float4*)ws_w;
#pragma unroll
        for (int t = 0; t < 12; ++t) wv[tid + t * 192] = Wv[tid + t * 192];
    }
#pragma unroll
    for (int t = 0; t < 4; ++t) {
        int q = tid + t * 192;
        int r = q / 24, c4 = q - r * 24;
        int row = row0 + r;
        float4 v = make_float4(0.f, 0.f, 0.f, 0.f);
        if (row < nrows) v = *(const float4*)&X[(long)row * DD + c4 * 4];
        *(float4*)&xs[r * 100 + c4 * 4] = v;
    }
    __syncthreads();
    const int je = tid % 24, ge = tid / 24;
    const int j0 = je * 4, r0 = ge * 4;
    float acc[4][4] = {};
#pragma unroll 4
    for (int k4 = 0; k4 < 24; ++k4) {
        const int kk = k4 * 4;
        float4 a0 = *(const float4*)&xs[(r0 + 0) * 100 + kk];
        float4 a1 = *(const float4*)&xs[(r0 + 1) * 100 + kk];
        float4 a2 = *(const float4*)&xs[(r0 + 2) * 100 + kk];
        float4 a3 = *(const float4*)&xs[(r0 + 3) * 100 + kk];
        float4 w0 = *(const float4*)&ws_w[(kk + 0) * DD + j0];
        float4 w1 = *(const float4*)&ws_w[(kk + 1) * DD + j0];
        float4 w2 = *(const float4*)&ws_w[(kk + 2) * DD + j0];
        float4 w3 = *(const float4*)&ws_w[(kk + 3) * DD + j0];
#define ROWFMA(i, a)                                                                  \
    acc[i][0] = fmaf(a.x, w0.x, fmaf(a.y, w1.x, fmaf(a.z, w2.x, fmaf(a.w, w3.x, acc[i][0])))); \
    acc[i][1] = fmaf(a.x, w0.y, fmaf(a.y, w1.y, fmaf(a.z, w2.y, fmaf(a.w, w3.y, acc[i][1])))); \
    acc[i][2] = fmaf(a.x, w0.z, fmaf(a.y, w1.z, fmaf(a.z, w2.z, fmaf(a.w, w3.z, acc[i][2])))); \
    acc[i][3] = fmaf(a.x, w0.w, fmaf(a.y, w1.w, fmaf(a.z, w2.w, fmaf(a.w, w3.w, acc[i][3]))));
        ROWFMA(0, a0) ROWFMA(1, a1) ROWFMA(2, a2) ROWFMA(3, a3)
#undef ROWFMA
    }
    const float b0 = B[j0], b1 = B[j0 + 1], b2 = B[j0 + 2], b3 = B[j0 + 3];
#pragma unroll
    for (int i = 0; i < 4; ++i) {
        int row = row0 + r0 + i;
        if (row >= nrows) continue;
        float v0 = acc[i][0] + b0, v1 = acc[i][1] + b1;
        float v2 = acc[i][2] + b2, v3 = acc[i][3] + b3;
        if (BFOUT) {
            u32 p0 = (u32)f2bf(v0) | ((u32)f2bf(v1) << 16);
            u32 p1 = (u32)f2bf(v2) | ((u32)f2bf(v3) << 16);
            *(uint2*)((u16*)Y + (long)row * DD + j0) = make_uint2(p0, p1);
        } else {
            *(float4*)((float*)Y + (long)row * DD + j0) = make_float4(v0, v1, v2, v3);
        }
    }
}

// Per-destination-node fused edge+aggregate kernel (edges sorted by dst).
// For node n with edges [r0,r1):
//   e_new = e@Cw + Cb + Dh[srcp] + Eh[n];  sigma = sigmoid(e_new)
//   e += relu(e_new) (in place, bf16);  num += Bh[srcp]*sigma; den += sigma
//   h[n] += relu(Ah[n] + num/(den+eps))
__global__ __launch_bounds__(192) void k_node_edge(u16* ebuf,
                                                   const float* __restrict__ Cw,
                                                   const float* __restrict__ Cb,
                                                   const u16* __restrict__ Dh,
                                                   const u16* __restrict__ Eh,
                                                   const u16* __restrict__ Bh,
                                                   const int* __restrict__ srcp,
                                                   const int* __restrict__ row_ptr,
                                                   const float* __restrict__ Ah,
                                                   float* __restrict__ hbuf) {
    __shared__ float cw[DD * DD];     // 36 KB
    __shared__ float xs[16 * 100];    // 6.4 KB
    __shared__ float redn[8][DD];     // 3 KB
    __shared__ float redd[8][DD];     // 3 KB
    __shared__ float sehn[DD];        // Eh[n] row
    __shared__ float scb[DD];         // Cb
    __shared__ int ssrc[16];
    const int tid = threadIdx.x;
    const int n = blockIdx.x;
    const int r0 = row_ptr[n], r1 = row_ptr[n + 1];
    {
        const float4* Wv = (const float4*)Cw;
        float4* wv = (float4*)cw;
#pragma unroll
        for (int t = 0; t < 12; ++t) wv[tid + t * 192] = Wv[tid + t * 192];
    }
    if (tid < DD) sehn[tid] = bf2f(Eh[(long)n * DD + tid]);
    else if (tid < 2 * DD) scb[tid - DD] = Cb[tid - DD];
    const int je = tid % 24, ge = tid / 24;
    const int j0 = je * 4, rl0 = ge * 2;
    float s_num[4] = {0.f, 0.f, 0.f, 0.f};
    float s_den[4] = {0.f, 0.f, 0.f, 0.f};

    for (int chunk = r0; chunk < r1; chunk += 16) {
        const int rows = min(16, r1 - chunk);
        // stage up to 16 e-rows (bf16 -> f32 LDS)
#pragma unroll
        for (int t = 0; t < 2; ++t) {
            int q = tid + t * 192;
            int r = q / 24, c4 = q - r * 24;
            float* xp = &xs[r * 100 + c4 * 4];
            if (r < rows) {
                uint2 u = *(const uint2*)&ebuf[(long)(chunk + r) * DD + c4 * 4];
                xp[0] = bf2f((u16)(u.x & 0xFFFF)); xp[1] = bf2f((u16)(u.x >> 16));
                xp[2] = bf2f((u16)(u.y & 0xFFFF)); xp[3] = bf2f((u16)(u.y >> 16));
            } else {
                xp[0] = 0.f; xp[1] = 0.f; xp[2] = 0.f; xp[3] = 0.f;
            }
        }
        if (tid < 16) ssrc[tid] = (chunk + tid < r1) ? srcp[chunk + tid] : 0;
        __syncthreads();
        // GEMM: 16x96 @ 96x96, each thread 2 rows x 4 cols
        float acc[2][4] = {};
#pragma unroll 4
        for (int k4 = 0; k4 < 24; ++k4) {
            const int kk = k4 * 4;
            float4 a0 = *(const float4*)&xs[(rl0 + 0) * 100 + kk];
            float4 a1 = *(const float4*)&xs[(rl0 + 1) * 100 + kk];
            float4 w0 = *(const float4*)&cw[(kk + 0) * DD + j0];
            float4 w1 = *(const float4*)&cw[(kk + 1) * DD + j0];
            float4 w2 = *(const float4*)&cw[(kk + 2) * DD + j0];
            float4 w3 = *(const float4*)&cw[(kk + 3) * DD + j0];
#define ROWFMA(i, a)                                                                  \
    acc[i][0] = fmaf(a.x, w0.x, fmaf(a.y, w1.x, fmaf(a.z, w2.x, fmaf(a.w, w3.x, acc[i][0])))); \
    acc[i][1] = fmaf(a.x, w0.y, fmaf(a.y, w1.y, fmaf(a.z, w2.y, fmaf(a.w, w3.y, acc[i][1])))); \
    acc[i][2] = fmaf(a.x, w0.z, fmaf(a.y, w1.z, fmaf(a.z, w2.z, fmaf(a.w, w3.z, acc[i][2])))); \
    acc[i][3] = fmaf(a.x, w0.w, fmaf(a.y, w1.w, fmaf(a.z, w2.w, fmaf(a.w, w3.w, acc[i][3]))));
            ROWFMA(0, a0) ROWFMA(1, a1)
#undef ROWFMA
        }
        // epilogue per local row
#pragma unroll
        for (int i = 0; i < 2; ++i) {
            const int rl = rl0 + i;
            if (rl < rows) {
                const long eg = chunk + rl;
                const int s = ssrc[rl];
                const uint2 du = *(const uint2*)&Dh[(long)s * DD + j0];
                const uint2 bu = *(const uint2*)&Bh[(long)s * DD + j0];
                float dh0 = bf2f((u16)(du.x & 0xFFFF)), dh1 = bf2f((u16)(du.x >> 16));
                float dh2 = bf2f((u16)(du.y & 0xFFFF)), dh3 = bf2f((u16)(du.y >> 16));
                float bh0 = bf2f((u16)(bu.x & 0xFFFF)), bh1 = bf2f((u16)(bu.x >> 16));
                float bh2 = bf2f((u16)(bu.y & 0xFFFF)), bh3 = bf2f((u16)(bu.y >> 16));
                float en0 = acc[i][0] + scb[j0 + 0] + dh0 + sehn[j0 + 0];
                float en1 = acc[i][1] + scb[j0 + 1] + dh1 + sehn[j0 + 1];
                float en2 = acc[i][2] + scb[j0 + 2] + dh2 + sehn[j0 + 2];
                float en3 = acc[i][3] + scb[j0 + 3] + dh3 + sehn[j0 + 3];
                float sg0 = 1.f / (1.f + __expf(-en0));
                float sg1 = 1.f / (1.f + __expf(-en1));
                float sg2 = 1.f / (1.f + __expf(-en2));
                float sg3 = 1.f / (1.f + __expf(-en3));
                s_num[0] += bh0 * sg0; s_den[0] += sg0;
                s_num[1] += bh1 * sg1; s_den[1] += sg1;
                s_num[2] += bh2 * sg2; s_den[2] += sg2;
                s_num[3] += bh3 * sg3; s_den[3] += sg3;
                const float* xp = &xs[rl * 100 + j0];
                float o0 = xp[0] + fmaxf(en0, 0.f), o1 = xp[1] + fmaxf(en1, 0.f);
                float o2 = xp[2] + fmaxf(en2, 0.f), o3 = xp[3] + fmaxf(en3, 0.f);
                u32 p0 = (u32)f2bf(o0) | ((u32)f2bf(o1) << 16);
                u32 p1 = (u32)f2bf(o2) | ((u32)f2bf(o3) << 16);
                *(uint2*)&ebuf[eg * DD + j0] = make_uint2(p0, p1);
            }
        }
        __syncthreads();   // xs reused next chunk
    }
    // cross-group reduction of num/den, then h update
#pragma unroll
    for (int c = 0; c < 4; ++c) { redn[ge][j0 + c] = s_num[c]; redd[ge][j0 + c] = s_den[c]; }
    __syncthreads();
    if (tid < DD) {
        float num = 0.f, den = 0.f;
#pragma unroll
        for (int g = 0; g < 8; ++g) { num += redn[g][tid]; den += redd[g][tid]; }
        float val = Ah[(long)n * DD + tid] + num / (den + EPSF);
        hbuf[(long)n * DD + tid] += fmaxf(val, 0.f);
    }
}

// small MLP stage, one thread per output element
__global__ void k_mlp(const float* __restrict__ X, const float* __restrict__ W,
                      const float* __restrict__ B, float* __restrict__ Y,
                      int K, int Dout, int act, long total) {
    long idx = (long)blockIdx.x * blockDim.x + threadIdx.x;
    if (idx >= total) return;
    int row = (int)(idx / Dout);
    int j = (int)(idx - (long)row * Dout);
    const float* xr = X + (long)row * K;
    float acc = B[j];
    for (int k = 0; k < K; ++k) acc = fmaf(xr[k], W[k * Dout + j], acc);
    if (act == 1) acc = fmaxf(acc, 0.f);
    else if (act == 2) acc = 1.f / (1.f + __expf(-acc));
    Y[idx] = acc;
}

extern "C" void kernel_launch(void* const* d_in, const int* in_sizes, int n_in,
                              void* d_out, int out_size, void* d_ws, size_t ws_size,
                              hipStream_t stream) {
    const float* h_in = (const float*)d_in[0];
    const float* e_in = (const float*)d_in[1];
    const int* src = (const int*)d_in[2];
    const int* dst = (const int*)d_in[3];
    const float* fp_w = (const float*)d_in[4];
    const float* fp_b = (const float*)d_in[5];
    const float* ep_w = (const float*)d_in[6];
    const float* ep_b = (const float*)d_in[7];
    const float* A_w = (const float*)d_in[8];
    const float* A_b = (const float*)d_in[9];
    const float* B_w = (const float*)d_in[10];
    const float* B_b = (const float*)d_in[11];
    const float* C_w = (const float*)d_in[12];
    const float* C_b = (const float*)d_in[13];
    const float* D_w = (const float*)d_in[14];
    const float* D_b = (const float*)d_in[15];
    const float* E_w = (const float*)d_in[16];
    const float* E_b = (const float*)d_in[17];
    const float* mlp0_w = (const float*)d_in[18];
    const float* mlp0_b = (const float*)d_in[19];
    const float* mlp1_w = (const float*)d_in[20];
    const float* mlp1_b = (const float*)d_in[21];
    const float* mlp2_w = (const float*)d_in[22];
    const float* mlp2_b = (const float*)d_in[23];
    float* out = (float*)d_out;

    const size_t ND = (size_t)NN * DD;
    const size_t ED = (size_t)NE * DD;
    char* w = (char*)d_ws;
    float* hbuf = (float*)w; w += ND * 4;
    float* Ahb  = (float*)w; w += ND * 4;
    u16* Bhb = (u16*)w; w += ND * 2;
    u16* Dhb = (u16*)w; w += ND * 2;
    u16* Ehb = (u16*)w; w += ND * 2;
    u16* ebuf = (u16*)w; w += ED * 2;
    int* counts  = (int*)w; w += (size_t)NN * 4;
    int* row_ptr = (int*)w; w += (size_t)(NN + 1) * 4 + 12;  // keep 16B align after
    int* cursor  = (int*)w; w += (size_t)NN * 4;
    int* eperm   = (int*)w; w += (size_t)NE * 4;
    int* srcp    = (int*)w; w += (size_t)NE * 4;
    size_t need = (size_t)(w - (char*)d_ws);
    if (ws_size < need) return;  // uniform -> graph-safe; fails absmax as diagnostic

    // CSR build (dst-sorted edge permutation)
    k_zero_i<<<(NN + 255) / 256, 256, 0, stream>>>(counts, NN);
    k_hist<<<(NE + 255) / 256, 256, 0, stream>>>(dst, counts);
    k_scan<<<1, 1024, 0, stream>>>(counts, row_ptr, cursor, NN);
    k_scatter<<<(NE + 255) / 256, 256, 0, stream>>>(src, dst, cursor, eperm, srcp);

    // input projections (edge proj lands in dst-sorted order)
    const long totH = (long)ND, totE = (long)ED;
    k_proj_h<<<(int)((totH + 255) / 256), 256, 0, stream>>>(h_in, fp_w, fp_b, hbuf, totH);
    k_proj_e<<<(int)((totE + 255) / 256), 256, 0, stream>>>(e_in, ep_w, ep_b, ebuf, eperm, totE);

    const int gN = (NN + 31) / 32;
    for (int l = 0; l < NL; ++l) {
        const float* Aw = A_w + (size_t)l * DD * DD; const float* Ab = A_b + (size_t)l * DD;
        const float* Bw = B_w + (size_t)l * DD * DD; const float* Bb = B_b + (size_t)l * DD;
        const float* Cw = C_w + (size_t)l * DD * DD; const float* Cb = C_b + (size_t)l * DD;
        const float* Dw = D_w + (size_t)l * DD * DD; const float* Db = D_b + (size_t)l * DD;
        const float* Ew = E_w + (size_t)l * DD * DD; const float* Eb = E_b + (size_t)l * DD;

        k_gemm96<false><<<gN, 192, 0, stream>>>(hbuf, Aw, Ab, Ahb, NN);
        k_gemm96<true><<<gN, 192, 0, stream>>>(hbuf, Bw, Bb, Bhb, NN);
        k_gemm96<true><<<gN, 192, 0, stream>>>(hbuf, Dw, Db, Dhb, NN);
        k_gemm96<true><<<gN, 192, 0, stream>>>(hbuf, Ew, Eb, Ehb, NN);

        k_node_edge<<<NN, 192, 0, stream>>>(ebuf, Cw, Cb, Dhb, Ehb, Bhb, srcp, row_ptr,
                                            Ahb, hbuf);
    }

    // MLP readout: 96 -> 48 (relu) -> 24 (relu) -> 10 (sigmoid). Reuse Ahb as temps.
    float* y1 = Ahb;                    // [N,48]
    float* y2 = Ahb + (size_t)NN * 48;  // [N,24]
    long t0 = (long)NN * 48, t1 = (long)NN * 24, t2 = (long)NN * NCLS;
    k_mlp<<<(int)((t0 + 255) / 256), 256, 0, stream>>>(hbuf, mlp0_w, mlp0_b, y1, DD, 48, 1, t0);
    k_mlp<<<(int)((t1 + 255) / 256), 256, 0, stream>>>(y1, mlp1_w, mlp1_b, y2, 48, 24, 1, t1);
    k_mlp<<<(int)((t2 + 255) / 256), 256, 0, stream>>>(y2, mlp2_w, mlp2_b, out, 24, NCLS, 2, t2);
}